// Round 18
// baseline (3244.647 us; speedup 1.0000x reference)
//
#include <hip/hip_runtime.h>
#include <stdint.h>

#define L_DIM 2048
#define B_DIM 32
#define D_DIM 1024
#define N_DIM 3072   // 3*D
#define K_DIM 1024
#define BD    32768  // B*D
#define S3    (32 * N_DIM)   // u3 step stride (ushorts)
#define LC    512            // chunk length
#define NGEMM 768            // gemm blocks per chunk
#define NREC  128            // rec blocks (x4 active waves = 512 waves, 2 blocks/CU)
#define NCVX  32             // fused convx blocks

typedef __bf16 bf16x8 __attribute__((ext_vector_type(8)));
typedef unsigned short ushort8 __attribute__((ext_vector_type(8)));
typedef float f32x4 __attribute__((ext_vector_type(4)));

typedef const __attribute__((address_space(1))) unsigned int* gq_t;
typedef __attribute__((address_space(3))) unsigned int* lq_t;

static __device__ __forceinline__ unsigned short f2bf(float f) {
  unsigned u = __float_as_uint(f);
  u += 0x7FFFu + ((u >> 16) & 1u);   // RNE
  return (unsigned short)(u >> 16);
}

static __device__ __forceinline__ float bf2f(unsigned short s) {
  return __uint_as_float(((unsigned)s) << 16);
}

// ---------- convert a chunk of x (f32) -> bf16, grid-stride, 8 elems/thread ----------
__global__ void k_convx(const float* __restrict__ x, unsigned short* __restrict__ xb, int n8) {
  for (int i = blockIdx.x * blockDim.x + threadIdx.x; i < n8; i += gridDim.x * blockDim.x) {
    const float4* p = reinterpret_cast<const float4*>(x) + (size_t)i * 2;
    float4 a = p[0], b = p[1];
    ushort8 o;
    o[0] = f2bf(a.x); o[1] = f2bf(a.y); o[2] = f2bf(a.z); o[3] = f2bf(a.w);
    o[4] = f2bf(b.x); o[5] = f2bf(b.y); o[6] = f2bf(b.z); o[7] = f2bf(b.w);
    reinterpret_cast<ushort8*>(xb)[i] = o;
  }
}

// ---------- W (K,N=3072 interleaved 3d+k) f32 -> WT (N'=k*D+d, K) bf16 ----------
__global__ __launch_bounds__(256) void k_wt(const float* __restrict__ w, unsigned short* __restrict__ wt) {
  __shared__ unsigned short tile[64][65];
  const int bid = blockIdx.x;
  const int kb = bid & 15;          // K/64 tile
  const int db = (bid >> 4) & 15;   // D/64 tile
  const int kp = bid >> 8;          // plane 0..2
  const int t = threadIdx.x;
  const int c = t & 63;
  const int q = t >> 6;             // 0..3
#pragma unroll
  for (int i = 0; i < 16; ++i) {
    int r = q * 16 + i;             // k within tile
    float v = w[(size_t)(kb * 64 + r) * N_DIM + 3 * (db * 64 + c) + kp];
    tile[r][c] = f2bf(v);
  }
  __syncthreads();
  const int k = t & 63;
#pragma unroll
  for (int i = 0; i < 16; ++i) {
    int n = q * 16 + i;             // d within tile
    wt[(size_t)(kp * D_DIM + db * 64 + n) * K_DIM + kb * 64 + k] = tile[k][n];
  }
}

// ---------- per-column bias, plane layout: col j = k*D+d ----------
__global__ void k_biascol(const float* __restrict__ bias, float* __restrict__ bc) {
  int j = blockIdx.x * blockDim.x + threadIdx.x;
  if (j >= N_DIM) return;
  int k = j >> 10;
  int d = j & 1023;
  float v = 0.f;
  if (k == 1) v = bias[d];
  else if (k == 2) v = bias[D_DIM + d];
  bc[j] = v;
}

// ---------- FUSED: [rec: chunk s-1] + [convx: chunk s+1] + [gemm: chunk s] ----------
// GEMM: 256x256 tile, BK=32, 64 KB LDS double-buffer -> 2 blocks/CU so
// co-resident blocks hide each other's barrier/load stalls.
// REC: 4 active waves/block (w>=4 exit), 128 blocks = 512 waves, 2 blocks/CU.
__global__ __launch_bounds__(512, 4) void k_fused(
    const unsigned short* __restrict__ A,    // gemm A chunk (bf16)
    const unsigned short* __restrict__ BT,   // (3072, K) bf16
    const float* __restrict__ bc,
    unsigned short* __restrict__ U,          // gemm out: u3 write buffer
    const unsigned short* __restrict__ xr,   // rec x chunk bf16
    const unsigned short* __restrict__ ur,   // rec u3 read buffer
    const float* __restrict__ wcv,
    const float* __restrict__ sxp,
    float* __restrict__ c_state,
    float* __restrict__ hr,                  // rec h chunk out (f32)
    const float* __restrict__ xc,            // convx src chunk (f32)
    unsigned short* __restrict__ xcb,        // convx dst chunk (bf16)
    int n_rec, int n_cvx, int n_gemm)
{
  __shared__ unsigned short smem[32768];   // 64 KB

  if ((int)blockIdx.x < n_rec) {
    // ================= REC path: 4 active waves x 64 chains =================
    const int tid = threadIdx.x;
    const int w = tid >> 6, t = tid & 63;
    if (w >= 4) return;
    unsigned short* ring = smem + w * 8192;      // 32 slots x 256 ushorts (512 B)
    const int wid = blockIdx.x * 4 + w;          // 0..511
    const int b  = wid >> 4;                     // batch 0..31
    const int d0 = (wid & 15) * 64;              // chain base
    const int ci = b * D_DIM + d0 + t;
    const int d  = d0 + t;

    const float fw = wcv[d];
    const float rw = wcv[D_DIM + d];
    const float sx = sxp[0];
    float c = c_state[ci];

    const int sub  = t >> 5;
    const int li   = t & 31;
    const int pp   = li >> 3;
    const int off8 = (li & 7) * 8;

#define RSTAGE(l2)                                                                        \
    { const int st_ = (l2) + sub;                                                         \
      const unsigned short* src_ = (pp < 3)                                               \
        ? ur + (size_t)st_ * S3 + b * N_DIM + pp * D_DIM + d0 + off8                      \
        : xr + (size_t)st_ * BD + b * D_DIM + d0 + off8;                                  \
      __builtin_amdgcn_global_load_lds((gq_t)src_, (lq_t)(ring + (((l2) & 31) << 8)), 16, 0, 0); }

#pragma unroll
    for (int i = 0; i < 8; ++i) RSTAGE(2 * i)
    asm volatile("s_waitcnt vmcnt(0)" ::: "memory");

    float* hp = hr + ci;
    for (int B = 0; B < LC; B += 16) {
#pragma unroll
      for (int i = 0; i < 8; ++i) {
        int ls = B + 16 + 2 * i;
        if (ls >= LC) ls -= LC;
        RSTAGE(ls)
      }
      float hv[16];
#pragma unroll
      for (int i = 0; i < 16; ++i) {
        const int sb = ((B + i) & 31) << 8;
        float u0 = bf2f(ring[sb + t]);
        float u1 = bf2f(ring[sb + 64 + t]);
        float u2 = bf2f(ring[sb + 128 + t]);
        float xv = bf2f(ring[sb + 192 + t]) * sx;
        float f = 1.f / (1.f + __expf(-(u1 + c * fw)));
        float r = 1.f / (1.f + __expf(-(u2 + c * rw)));
        c = u0 + (c - u0) * f;
        hv[i] = xv + (c - xv) * r;
      }
#pragma unroll
      for (int i = 0; i < 16; ++i)
        hp[(size_t)(B + i) * BD] = hv[i];
      asm volatile("s_waitcnt vmcnt(16)" ::: "memory");
    }
    c_state[ci] = c;
#undef RSTAGE
    return;
  }

  if ((int)blockIdx.x < n_rec + n_cvx) {
    // ================= CONVX path: convert chunk s+1 (f32 -> bf16) =================
    const int n8 = LC * BD / 8;
    for (int i = ((int)blockIdx.x - n_rec) * 512 + threadIdx.x; i < n8; i += n_cvx * 512) {
      const float4* p = reinterpret_cast<const float4*>(xc) + (size_t)i * 2;
      float4 a = p[0], b = p[1];
      ushort8 o;
      o[0] = f2bf(a.x); o[1] = f2bf(a.y); o[2] = f2bf(a.z); o[3] = f2bf(a.w);
      o[4] = f2bf(b.x); o[5] = f2bf(b.y); o[6] = f2bf(b.z); o[7] = f2bf(b.w);
      reinterpret_cast<ushort8*>(xcb)[i] = o;
    }
    return;
  }

  // ================= GEMM path: 256x256, BK=32, 64KB dbuf, 2 blocks/CU =================
  const int gid = (int)blockIdx.x - n_rec - n_cvx;
  const int nwg = n_gemm;
  const int q8 = nwg >> 3, r8 = nwg & 7;
  const int xcd = gid & 7, li2 = gid >> 3;
  const int wg = (xcd < r8 ? xcd * (q8 + 1) : r8 * (q8 + 1) + (xcd - r8) * q8) + li2;
  const int NT = N_DIM / 256;   // 12
  const int bn = wg % NT;
  const int bm = wg / NT;

  const int t  = threadIdx.x;
  const int w  = t >> 6;
  const int l  = t & 63;
  const int wr = w >> 2, wc = w & 3;
  const int wrb = wr * 128, wcb = wc * 64;
  const int l15 = l & 15, lg = l >> 4;
  const int kgp = ((lg ^ ((l15 >> 1) & 3)) << 3);   // swizzled k-octet (4 octets/row)
  // staging: instr II covers slots II*512+t: row = r0+II*128, octet o0 (swizzle key (row>>1)&3)
  const int r0 = t >> 2;
  const int o0 = (t & 3) ^ ((t >> 3) & 3);

  const unsigned short* Abase = A  + (size_t)(bm * 256) * K_DIM;
  const unsigned short* Bbase = BT + (size_t)(bn * 256) * K_DIM;

  f32x4 acc[8][4];
#pragma unroll
  for (int i = 0; i < 8; ++i)
#pragma unroll
    for (int j = 0; j < 4; ++j) acc[i][j] = f32x4{0.f, 0.f, 0.f, 0.f};

#define SGI(G, T, ldsBase, II)                                                          \
  __builtin_amdgcn_global_load_lds(                                                     \
    (gq_t)((G) + (size_t)(r0 + (II) * 128) * K_DIM + (T) * 32 + o0 * 8),                \
    (lq_t)&smem[(ldsBase) + ((II) * 512 + t) * 8], 16, 0, 0);

#define SBa(T,b) SGI(Bbase, (T), (b) * 16384 + 8192, 0)
#define SBb(T,b) SGI(Bbase, (T), (b) * 16384 + 8192, 1)
#define SAa(T,b) SGI(Abase, (T), (b) * 16384, 0)
#define SAb(T,b) SGI(Abase, (T), (b) * 16384, 1)

#define LDF(idx) __builtin_bit_cast(bf16x8, *reinterpret_cast<const ushort8*>(&smem[(idx)]))

  // prologue: tile0 fully + SBa(1); wait tile0 (4 ops), SBa(1) stays in flight
  SBa(0, 0); SBb(0, 0); SAa(0, 0); SAb(0, 0); SBa(1, 1);
  asm volatile("s_waitcnt vmcnt(1)" ::: "memory");
  __builtin_amdgcn_s_barrier();

#pragma unroll 2
  for (int t0 = 0; t0 < 32; ++t0) {
    const int cur = t0 & 1, nxt = cur ^ 1;
    const int cA = cur * 16384, cB = cA + 8192;
    bf16x8 bfr[4];
#pragma unroll
    for (int q = 0; q < 4; ++q) {
      bf16x8 af[2];
      if (q == 0) {
#pragma unroll
        for (int nf = 0; nf < 4; ++nf)
          bfr[nf] = LDF(cB + (wcb + nf * 16 + l15) * 32 + kgp);
      }
#pragma unroll
      for (int mf = 0; mf < 2; ++mf)
        af[mf] = LDF(cA + (wrb + (q * 2 + mf) * 16 + l15) * 32 + kgp);

      if (q == 0 && t0 < 31) SBb(t0 + 1, nxt);
      if (q == 1 && t0 < 31) SAa(t0 + 1, nxt);
      if (q == 2 && t0 < 31) SAb(t0 + 1, nxt);
      if (q == 3 && t0 < 30) SBa(t0 + 2, cur);

      __builtin_amdgcn_s_barrier();
      __builtin_amdgcn_s_setprio(1);
#pragma unroll
      for (int mf = 0; mf < 2; ++mf)
#pragma unroll
        for (int nf = 0; nf < 4; ++nf)
          acc[q * 2 + mf][nf] = __builtin_amdgcn_mfma_f32_16x16x32_bf16(af[mf], bfr[nf], acc[q * 2 + mf][nf], 0, 0, 0);
      __builtin_amdgcn_s_setprio(0);
      if (q == 3) {
        if (t0 < 30)       asm volatile("s_waitcnt vmcnt(1)" ::: "memory");
        else if (t0 == 30) asm volatile("s_waitcnt vmcnt(0)" ::: "memory");
      }
      __builtin_amdgcn_s_barrier();
      __builtin_amdgcn_sched_barrier(0);
    }
  }

  // ---- epilogue: bias add, f32->bf16, store
  const int r4 = lg * 4;
  float badd[4];
#pragma unroll
  for (int nf = 0; nf < 4; ++nf) badd[nf] = bc[bn * 256 + wcb + nf * 16 + l15];
#pragma unroll
  for (int fm = 0; fm < 8; ++fm) {
    const int row = bm * 256 + wrb + fm * 16 + r4;
#pragma unroll
    for (int nf = 0; nf < 4; ++nf) {
      const int col = bn * 256 + wcb + nf * 16 + l15;
      unsigned short* out = U + (size_t)row * N_DIM + col;
#pragma unroll
      for (int i = 0; i < 4; ++i)
        out[(size_t)i * N_DIM] = f2bf(acc[fm][nf][i] + badd[nf]);
    }
  }
#undef SGI
#undef SBa
#undef SBb
#undef SAa
#undef SAb
#undef LDF
}

__global__ void k_copyc(const float* __restrict__ c_state, float* __restrict__ out) {
  int i = blockIdx.x * blockDim.x + threadIdx.x;
  if (i < BD) out[i] = c_state[i];
}

extern "C" void kernel_launch(void* const* d_in, const int* in_sizes, int n_in,
                              void* d_out, int out_size, void* d_ws, size_t ws_size,
                              hipStream_t stream) {
  const float* x    = (const float*)d_in[0];
  const float* w    = (const float*)d_in[1];
  const float* wcv  = (const float*)d_in[2];
  const float* bias = (const float*)d_in[3];
  const float* sx   = (const float*)d_in[4];
  float* hout = (float*)d_out;
  float* cout = hout + (size_t)L_DIM * BD;

  const size_t wt_bytes  = (size_t)N_DIM * K_DIM * 2;
  const size_t bc_off    = wt_bytes;
  const size_t c_off     = bc_off + (size_t)N_DIM * 4;
  const size_t xbf_off   = c_off + (size_t)BD * 4;
  const size_t xbf_bytes = (size_t)L_DIM * BD * 2;            // 134 MB
  const size_t u3_off    = xbf_off + xbf_bytes;
  const size_t u3_elems  = (size_t)LC * BD * 3;               // per buffer (ushorts)

  char* wsb = (char*)d_ws;
  unsigned short* wt_p  = (unsigned short*)wsb;
  float*          bc_p  = (float*)(wsb + bc_off);
  float*          c_p   = (float*)(wsb + c_off);
  unsigned short* xbf_p = (unsigned short*)(wsb + xbf_off);
  unsigned short* u3_0  = (unsigned short*)(wsb + u3_off);
  unsigned short* u3_1  = u3_0 + u3_elems;

  hipMemsetAsync(c_p, 0, (size_t)BD * 4, stream);
  k_wt<<<(K_DIM / 64) * (D_DIM / 64) * 3, 256, 0, stream>>>(w, wt_p);
  k_biascol<<<(N_DIM + 255) / 256, 256, 0, stream>>>(bias, bc_p);
  // chunk 0 conversion only; chunks 1..3 fused into the pipeline
  k_convx<<<512, 256, 0, stream>>>(x, xbf_p, LC * BD / 8);

  const int nchunks = L_DIM / LC;   // 4
  for (int s = 0; s <= nchunks; ++s) {
    const int ng = (s < nchunks) ? NGEMM : 0;
    const int nr = (s > 0) ? NREC : 0;
    const int nc = (s < nchunks - 1) ? NCVX : 0;     // convert chunk s+1
    const int rs = (s > 0) ? (s - 1) : 0;
    const int cs = s + 1;
    unsigned short* uw = (s & 1) ? u3_1 : u3_0;          // gemm writes
    const unsigned short* urd = (rs & 1) ? u3_1 : u3_0;  // rec reads
    k_fused<<<ng + nr + nc, 512, 0, stream>>>(
        xbf_p + (size_t)(s < nchunks ? s : 0) * LC * BD, wt_p, bc_p, uw,
        xbf_p + (size_t)rs * LC * BD, urd, wcv, sx, c_p,
        hout + (size_t)rs * LC * BD,
        x + (size_t)(nc ? cs : 0) * LC * BD,
        xbf_p + (size_t)(nc ? cs : 0) * LC * BD,
        nr, nc, ng);
  }
  k_copyc<<<BD / 256, 256, 0, stream>>>(c_p, cout);
}

// Round 19
// 709.608 us; speedup vs baseline: 4.5724x; 4.5724x over previous
//
#include <hip/hip_runtime.h>
#include <stdint.h>

#define L_DIM 2048
#define B_DIM 32
#define D_DIM 1024
#define N_DIM 3072   // 3*D
#define K_DIM 1024
#define BD    32768  // B*D
#define S3    (32 * N_DIM)   // u3 step stride (ushorts)
#define LC    512            // chunk length
#define NGEMM 768            // gemm blocks per chunk
#define NREC  64             // rec blocks (x8 waves = 512 waves)
#define NCVX  32             // fused convx blocks

typedef __bf16 bf16x8 __attribute__((ext_vector_type(8)));
typedef unsigned short ushort8 __attribute__((ext_vector_type(8)));
typedef float f32x4 __attribute__((ext_vector_type(4)));

typedef const __attribute__((address_space(1))) unsigned int* gq_t;
typedef __attribute__((address_space(3))) unsigned int* lq_t;

static __device__ __forceinline__ unsigned short f2bf(float f) {
  unsigned u = __float_as_uint(f);
  u += 0x7FFFu + ((u >> 16) & 1u);   // RNE
  return (unsigned short)(u >> 16);
}

static __device__ __forceinline__ float bf2f(unsigned short s) {
  return __uint_as_float(((unsigned)s) << 16);
}

// ---------- convert a chunk of x (f32) -> bf16, grid-stride, 8 elems/thread ----------
__global__ void k_convx(const float* __restrict__ x, unsigned short* __restrict__ xb, int n8) {
  for (int i = blockIdx.x * blockDim.x + threadIdx.x; i < n8; i += gridDim.x * blockDim.x) {
    const float4* p = reinterpret_cast<const float4*>(x) + (size_t)i * 2;
    float4 a = p[0], b = p[1];
    ushort8 o;
    o[0] = f2bf(a.x); o[1] = f2bf(a.y); o[2] = f2bf(a.z); o[3] = f2bf(a.w);
    o[4] = f2bf(b.x); o[5] = f2bf(b.y); o[6] = f2bf(b.z); o[7] = f2bf(b.w);
    reinterpret_cast<ushort8*>(xb)[i] = o;
  }
}

// ---------- W (K,N=3072 interleaved 3d+k) f32 -> WT (N'=k*D+d, K) bf16 ----------
__global__ __launch_bounds__(256) void k_wt(const float* __restrict__ w, unsigned short* __restrict__ wt) {
  __shared__ unsigned short tile[64][65];
  const int bid = blockIdx.x;
  const int kb = bid & 15;          // K/64 tile
  const int db = (bid >> 4) & 15;   // D/64 tile
  const int kp = bid >> 8;          // plane 0..2
  const int t = threadIdx.x;
  const int c = t & 63;
  const int q = t >> 6;             // 0..3
#pragma unroll
  for (int i = 0; i < 16; ++i) {
    int r = q * 16 + i;             // k within tile
    float v = w[(size_t)(kb * 64 + r) * N_DIM + 3 * (db * 64 + c) + kp];
    tile[r][c] = f2bf(v);
  }
  __syncthreads();
  const int k = t & 63;
#pragma unroll
  for (int i = 0; i < 16; ++i) {
    int n = q * 16 + i;             // d within tile
    wt[(size_t)(kp * D_DIM + db * 64 + n) * K_DIM + kb * 64 + k] = tile[k][n];
  }
}

// ---------- per-column bias, plane layout: col j = k*D+d ----------
__global__ void k_biascol(const float* __restrict__ bias, float* __restrict__ bc) {
  int j = blockIdx.x * blockDim.x + threadIdx.x;
  if (j >= N_DIM) return;
  int k = j >> 10;
  int d = j & 1023;
  float v = 0.f;
  if (k == 1) v = bias[d];
  else if (k == 2) v = bias[D_DIM + d];
  bc[j] = v;
}

// ---------- FUSED: [rec: chunk s-1] + [convx: chunk s+1] + [gemm: chunk s] ----------
// All roles touch disjoint buffers; dependencies cross launch boundaries only
// (stream-ordered). Block order: rec (longest) -> convx (frees CUs after ~16us)
// -> gemm (fills remaining rounds).
__global__ __launch_bounds__(512, 2) void k_fused(
    const unsigned short* __restrict__ A,    // gemm A chunk (bf16)
    const unsigned short* __restrict__ BT,   // (3072, K) bf16
    const float* __restrict__ bc,
    unsigned short* __restrict__ U,          // gemm out: u3 write buffer
    const unsigned short* __restrict__ xr,   // rec x chunk bf16
    const unsigned short* __restrict__ ur,   // rec u3 read buffer
    const float* __restrict__ wcv,
    const float* __restrict__ sxp,
    float* __restrict__ c_state,
    float* __restrict__ hr,                  // rec h chunk out (f32)
    const float* __restrict__ xc,            // convx src chunk (f32)
    unsigned short* __restrict__ xcb,        // convx dst chunk (bf16)
    int n_rec, int n_cvx, int n_gemm)
{
  __shared__ unsigned short smem[65536];   // gemm: dbuf tiles; rec: 8 x 16KB rings

  if ((int)blockIdx.x < n_rec) {
    // ================= REC path: 8 independent waves x 64 chains =================
    const int tid = threadIdx.x;
    const int w = tid >> 6, t = tid & 63;
    unsigned short* ring = smem + w * 8192;      // 32 slots x 256 ushorts (512 B)
    const int wid = blockIdx.x * 8 + w;          // 0..511
    const int b  = wid >> 4;                     // batch 0..31
    const int d0 = (wid & 15) * 64;              // chain base
    const int ci = b * D_DIM + d0 + t;
    const int d  = d0 + t;

    const float fw = wcv[d];
    const float rw = wcv[D_DIM + d];
    const float sx = sxp[0];
    float c = c_state[ci];

    const int sub  = t >> 5;
    const int li   = t & 31;
    const int pp   = li >> 3;
    const int off8 = (li & 7) * 8;

#define RSTAGE(l2)                                                                        \
    { const int st_ = (l2) + sub;                                                         \
      const unsigned short* src_ = (pp < 3)                                               \
        ? ur + (size_t)st_ * S3 + b * N_DIM + pp * D_DIM + d0 + off8                      \
        : xr + (size_t)st_ * BD + b * D_DIM + d0 + off8;                                  \
      __builtin_amdgcn_global_load_lds((gq_t)src_, (lq_t)(ring + (((l2) & 31) << 8)), 16, 0, 0); }

#pragma unroll
    for (int i = 0; i < 8; ++i) RSTAGE(2 * i)
    asm volatile("s_waitcnt vmcnt(0)" ::: "memory");

    float* hp = hr + ci;
    for (int B = 0; B < LC; B += 16) {
#pragma unroll
      for (int i = 0; i < 8; ++i) {
        int ls = B + 16 + 2 * i;
        if (ls >= LC) ls -= LC;
        RSTAGE(ls)
      }
      float hv[16];
#pragma unroll
      for (int i = 0; i < 16; ++i) {
        const int sb = ((B + i) & 31) << 8;
        float u0 = bf2f(ring[sb + t]);
        float u1 = bf2f(ring[sb + 64 + t]);
        float u2 = bf2f(ring[sb + 128 + t]);
        float xv = bf2f(ring[sb + 192 + t]) * sx;
        float f = 1.f / (1.f + __expf(-(u1 + c * fw)));
        float r = 1.f / (1.f + __expf(-(u2 + c * rw)));
        c = u0 + (c - u0) * f;
        hv[i] = xv + (c - xv) * r;
      }
#pragma unroll
      for (int i = 0; i < 16; ++i)
        hp[(size_t)(B + i) * BD] = hv[i];
      asm volatile("s_waitcnt vmcnt(16)" ::: "memory");
    }
    c_state[ci] = c;
#undef RSTAGE
    return;
  }

  if ((int)blockIdx.x < n_rec + n_cvx) {
    // ================= CONVX path: convert chunk s+1 (f32 -> bf16) =================
    const int n8 = LC * BD / 8;
    for (int i = ((int)blockIdx.x - n_rec) * 512 + threadIdx.x; i < n8; i += n_cvx * 512) {
      const float4* p = reinterpret_cast<const float4*>(xc) + (size_t)i * 2;
      float4 a = p[0], b = p[1];
      ushort8 o;
      o[0] = f2bf(a.x); o[1] = f2bf(a.y); o[2] = f2bf(a.z); o[3] = f2bf(a.w);
      o[4] = f2bf(b.x); o[5] = f2bf(b.y); o[6] = f2bf(b.z); o[7] = f2bf(b.w);
      reinterpret_cast<ushort8*>(xcb)[i] = o;
    }
    return;
  }

  // ================= GEMM path (r13-verified 8-phase schedule) =================
  const int gid = (int)blockIdx.x - n_rec - n_cvx;
  const int nwg = n_gemm;
  const int q8 = nwg >> 3, r8 = nwg & 7;
  const int xcd = gid & 7, li2 = gid >> 3;
  const int wg = (xcd < r8 ? xcd * (q8 + 1) : r8 * (q8 + 1) + (xcd - r8) * q8) + li2;
  const int NT = N_DIM / 256;   // 12
  const int bn = wg % NT;
  const int bm = wg / NT;

  const int t  = threadIdx.x;
  const int w  = t >> 6;
  const int l  = t & 63;
  const int wr = w >> 2, wc = w & 3;
  const int wrb = wr * 128, wcb = wc * 64;
  const int l15 = l & 15, lg = l >> 4, lx = l & 7;
  const int kgp0 = (lg ^ lx) * 8;
  const int kgp1 = ((4 + lg) ^ lx) * 8;
  const int sr0 = w * 8 + (l >> 3);
  const int kgs = (lx ^ (l >> 3)) * 8;

  const unsigned short* Abase = A  + (size_t)(bm * 256) * K_DIM;
  const unsigned short* Bbase = BT + (size_t)(bn * 256) * K_DIM;

  f32x4 acc[8][4];
#pragma unroll
  for (int i = 0; i < 8; ++i)
#pragma unroll
    for (int j = 0; j < 4; ++j) acc[i][j] = f32x4{0.f, 0.f, 0.f, 0.f};

#define STAGE(G, growbase, T, ldsBase)                                                  \
  { const unsigned short* s0_ = (G) + (((size_t)((growbase) + sr0)) << 10) + (T) * 64 + kgs; \
    __builtin_amdgcn_global_load_lds((gq_t)s0_, (lq_t)&smem[(ldsBase) + w * 512], 16, 0, 0); \
    const unsigned short* s1_ = s0_ + (64 << 10);                                       \
    __builtin_amdgcn_global_load_lds((gq_t)s1_, (lq_t)&smem[(ldsBase) + 4096 + w * 512], 16, 0, 0); }

#define SB0(T, b) STAGE(Bbase, 0,   (T), (b) * 32768 + 16384)
#define SB1(T, b) STAGE(Bbase, 128, (T), (b) * 32768 + 16384 + 8192)
#define SA0(T, b) STAGE(Abase, 0,   (T), (b) * 32768)
#define SA1(T, b) STAGE(Abase, 128, (T), (b) * 32768 + 8192)

#define LDF(idx) __builtin_bit_cast(bf16x8, *reinterpret_cast<const ushort8*>(&smem[(idx)]))

  SB0(0, 0); SB1(0, 0); SA0(0, 0); SA1(0, 0); SB0(1, 1);
  asm volatile("s_waitcnt vmcnt(2)" ::: "memory");
  __builtin_amdgcn_s_barrier();

#pragma unroll 2
  for (int t0 = 0; t0 < 16; ++t0) {
    const int cur = t0 & 1, nxt = cur ^ 1;
    const int cA = cur * 32768, cB = cA + 16384;
    bf16x8 bfr[4][2];
#pragma unroll
    for (int q = 0; q < 4; ++q) {
      bf16x8 af[2][2];
      if (q == 0) {
#pragma unroll
        for (int nf = 0; nf < 4; ++nf) {
          const int nr = (wcb + nf * 16 + l15) * 64;
          bfr[nf][0] = LDF(cB + nr + kgp0);
          bfr[nf][1] = LDF(cB + nr + kgp1);
        }
      }
#pragma unroll
      for (int mf = 0; mf < 2; ++mf) {
        const int ar = (wrb + (q * 2 + mf) * 16 + l15) * 64;
        af[mf][0] = LDF(cA + ar + kgp0);
        af[mf][1] = LDF(cA + ar + kgp1);
      }
      if (q == 0 && t0 < 15) SB1(t0 + 1, nxt);
      if (q == 1 && t0 < 15) SA0(t0 + 1, nxt);
      if (q == 2 && t0 < 15) SA1(t0 + 1, nxt);
      if (q == 3 && t0 < 14) SB0(t0 + 2, cur);

      __builtin_amdgcn_s_barrier();
      __builtin_amdgcn_s_setprio(1);
#pragma unroll
      for (int mf = 0; mf < 2; ++mf)
#pragma unroll
        for (int nf = 0; nf < 4; ++nf) {
          acc[q * 2 + mf][nf] = __builtin_amdgcn_mfma_f32_16x16x32_bf16(af[mf][0], bfr[nf][0], acc[q * 2 + mf][nf], 0, 0, 0);
          acc[q * 2 + mf][nf] = __builtin_amdgcn_mfma_f32_16x16x32_bf16(af[mf][1], bfr[nf][1], acc[q * 2 + mf][nf], 0, 0, 0);
        }
      __builtin_amdgcn_s_setprio(0);
      if (q == 3) {
        if (t0 < 14)       asm volatile("s_waitcnt vmcnt(2)" ::: "memory");
        else if (t0 == 14) asm volatile("s_waitcnt vmcnt(0)" ::: "memory");
      }
      __builtin_amdgcn_s_barrier();
      __builtin_amdgcn_sched_barrier(0);
    }
  }

  const int r4 = lg * 4;
  float badd[4];
#pragma unroll
  for (int nf = 0; nf < 4; ++nf) badd[nf] = bc[bn * 256 + wcb + nf * 16 + l15];
#pragma unroll
  for (int fm = 0; fm < 8; ++fm) {
    const int row = bm * 256 + wrb + fm * 16 + r4;
#pragma unroll
    for (int nf = 0; nf < 4; ++nf) {
      const int col = bn * 256 + wcb + nf * 16 + l15;
      unsigned short* out = U + (size_t)row * N_DIM + col;
#pragma unroll
      for (int i = 0; i < 4; ++i)
        out[(size_t)i * N_DIM] = f2bf(acc[fm][nf][i] + badd[nf]);
    }
  }
#undef STAGE
#undef SB0
#undef SB1
#undef SA0
#undef SA1
#undef LDF
}

__global__ void k_copyc(const float* __restrict__ c_state, float* __restrict__ out) {
  int i = blockIdx.x * blockDim.x + threadIdx.x;
  if (i < BD) out[i] = c_state[i];
}

extern "C" void kernel_launch(void* const* d_in, const int* in_sizes, int n_in,
                              void* d_out, int out_size, void* d_ws, size_t ws_size,
                              hipStream_t stream) {
  const float* x    = (const float*)d_in[0];
  const float* w    = (const float*)d_in[1];
  const float* wcv  = (const float*)d_in[2];
  const float* bias = (const float*)d_in[3];
  const float* sx   = (const float*)d_in[4];
  float* hout = (float*)d_out;
  float* cout = hout + (size_t)L_DIM * BD;

  const size_t wt_bytes  = (size_t)N_DIM * K_DIM * 2;
  const size_t bc_off    = wt_bytes;
  const size_t c_off     = bc_off + (size_t)N_DIM * 4;
  const size_t xbf_off   = c_off + (size_t)BD * 4;
  const size_t xbf_bytes = (size_t)L_DIM * BD * 2;            // 134 MB
  const size_t u3_off    = xbf_off + xbf_bytes;
  const size_t u3_elems  = (size_t)LC * BD * 3;               // per buffer (ushorts)

  char* wsb = (char*)d_ws;
  unsigned short* wt_p  = (unsigned short*)wsb;
  float*          bc_p  = (float*)(wsb + bc_off);
  float*          c_p   = (float*)(wsb + c_off);
  unsigned short* xbf_p = (unsigned short*)(wsb + xbf_off);
  unsigned short* u3_0  = (unsigned short*)(wsb + u3_off);
  unsigned short* u3_1  = u3_0 + u3_elems;

  hipMemsetAsync(c_p, 0, (size_t)BD * 4, stream);
  k_wt<<<(K_DIM / 64) * (D_DIM / 64) * 3, 256, 0, stream>>>(w, wt_p);
  k_biascol<<<(N_DIM + 255) / 256, 256, 0, stream>>>(bias, bc_p);
  // chunk 0 conversion only; chunks 1..3 fused into the pipeline
  k_convx<<<512, 256, 0, stream>>>(x, xbf_p, LC * BD / 8);

  const int nchunks = L_DIM / LC;   // 4
  for (int s = 0; s <= nchunks; ++s) {
    const int ng = (s < nchunks) ? NGEMM : 0;
    const int nr = (s > 0) ? NREC : 0;
    const int nc = (s < nchunks - 1) ? NCVX : 0;     // convert chunk s+1
    const int rs = (s > 0) ? (s - 1) : 0;
    const int cs = s + 1;
    unsigned short* uw = (s & 1) ? u3_1 : u3_0;          // gemm writes
    const unsigned short* urd = (rs & 1) ? u3_1 : u3_0;  // rec reads
    k_fused<<<ng + nr + nc, 512, 0, stream>>>(
        xbf_p + (size_t)(s < nchunks ? s : 0) * LC * BD, wt_p, bc_p, uw,
        xbf_p + (size_t)rs * LC * BD, urd, wcv, sx, c_p,
        hout + (size_t)rs * LC * BD,
        x + (size_t)(nc ? cs : 0) * LC * BD,
        xbf_p + (size_t)(nc ? cs : 0) * LC * BD,
        nr, nc, ng);
  }
  k_copyc<<<BD / 256, 256, 0, stream>>>(c_p, cout);
}